// Round 9
// baseline (349.810 us; speedup 1.0000x reference)
//
#include <hip/hip_runtime.h>
#include <math.h>

// SelfSimilarity — R9 = R7 code EXACTLY, but launcher replays kernels for timing
// decomposition: prep + 2x phase1 + 3x phase2 (all idempotent -> same output).
// dur9 = prep + 2*p1 + 3*p2;  R7: prep + p1 + p2 = 132.0 us  =>  p2 = dur9 - 260.
//
// out[b,n,m] = softmax_m( -(|x_n|^2+|x_m|^2-2 x_n.x_m)/T )
//            = e_m / sum_m e_m,   e_m = exp2( kexp*dot(x_n,x_m) - 0.5*kexp*|x_m|^2 )
// phase1 (rowsum): SINGLE product ah.bh; diagonal error corrected exactly at
//   normalization: sum' = sum - e1_diag + exp2(-csq[R]) (true rescaled diagonal).
// phase2 (store): 3-product ah.bh+ah.bl+al.bh; rinv folded pre-LDS,
//   LDS-staged epilogue -> linear nontemporal float4 stores.

constexpr int NB = 4;
constexpr int N = 4096;
constexpr int D = 64;
constexpr float TEMP = 13.544f;
constexpr int CSPL = 4;
constexpr int COLS = N / CSPL;           // 1024 cols per block
constexpr int TMB = 32;                  // rows per block
constexpr int NW = 4;
constexpr int THREADS = 256;
constexpr int TILES = COLS / (NW * 16);  // 16 col-tiles (of 64 cols) per block

typedef __attribute__((ext_vector_type(8))) short bf16x8;
typedef __attribute__((ext_vector_type(4))) float f32x4;

__device__ __forceinline__ unsigned short f2bf(float f) {
    unsigned int u = __builtin_bit_cast(unsigned int, f);
    u += 0x7FFFu + ((u >> 16) & 1u);   // RNE
    return (unsigned short)(u >> 16);
}
__device__ __forceinline__ float bf2f(unsigned short h) {
    return __builtin_bit_cast(float, (unsigned int)h << 16);
}

// LDS float-index of the 4-float group written by (wave w, kgroup kg, lanerow lr, acc)
__device__ __forceinline__ int lidx(int w, int kg, int lr, int acc) {
    return ((((w << 6) + (kg << 4) + lr) << 3) + (acc << 2)) ^ (w << 2);
}

// ---------------- Pre-pass: convert + squares ----------------
__global__ __launch_bounds__(THREADS)
void prep_kernel(const float* __restrict__ x,
                 short* __restrict__ xhi, short* __restrict__ xlo,
                 short* __restrict__ xhs, short* __restrict__ xls,
                 float* __restrict__ csq) {
    const int t = threadIdx.x;
    const int lane = t & 63, w = t >> 6;
    const int row = blockIdx.x * 32 + w * 8 + (lane >> 3);
    const int seg = lane & 7;
    const float S = 2.0f * 1.4426950408889634f / TEMP;   // kexp

    const float* p = x + (size_t)row * D + seg * 8;
    const float4 u = *reinterpret_cast<const float4*>(p);
    const float4 v = *reinterpret_cast<const float4*>(p + 4);
    float e[8] = {u.x, u.y, u.z, u.w, v.x, v.y, v.z, v.w};

    float sq = 0.f;
    #pragma unroll
    for (int j = 0; j < 8; ++j) sq += e[j] * e[j];
    sq += __shfl_xor(sq, 1, 64);
    sq += __shfl_xor(sq, 2, 64);
    sq += __shfl_xor(sq, 4, 64);

    bf16x8 h, l, hs, ls;
    #pragma unroll
    for (int j = 0; j < 8; ++j) {
        const unsigned short hb = f2bf(e[j]);
        h[j] = (short)hb;
        l[j] = (short)f2bf(e[j] - bf2f(hb));
        const float es = e[j] * S;
        const unsigned short hsb = f2bf(es);
        hs[j] = (short)hsb;
        ls[j] = (short)f2bf(es - bf2f(hsb));
    }
    const int off = row * D + seg * 8;
    *reinterpret_cast<bf16x8*>(xhi + off) = h;
    *reinterpret_cast<bf16x8*>(xlo + off) = l;
    *reinterpret_cast<bf16x8*>(xhs + off) = hs;
    *reinterpret_cast<bf16x8*>(xls + off) = ls;
    if (seg == 0) csq[row] = -0.5f * S * sq;
}

// ---------------- Main sweep: rowsum / normalize+store ----------------
template<bool STORE>
__global__ __launch_bounds__(THREADS)
void sweep_kernel(const short* __restrict__ xhi, const short* __restrict__ xlo,
                  const short* __restrict__ xhs, const short* __restrict__ xls,
                  const float* __restrict__ csq, float* __restrict__ parts,
                  float* __restrict__ out) {
    const int b = blockIdx.y;
    const int s = blockIdx.z;
    const int row0 = blockIdx.x * TMB;
    const int t = threadIdx.x;
    const int w = t >> 6, lane = t & 63;
    const int lr = lane & 15, kg = lane >> 4;
    const int rbase = b * N;

    // persistent row-side fragments (MFMA B operand), rows row0 + 16*i + lr
    bf16x8 bh[2][2], bl[2][2];
    #pragma unroll
    for (int i = 0; i < 2; ++i) {
        const int r = rbase + row0 + 16 * i + lr;
        const short* ph = xhi + r * D + kg * 8;
        #pragma unroll
        for (int kt = 0; kt < 2; ++kt)
            bh[i][kt] = *reinterpret_cast<const bf16x8*>(ph + kt * 32);
        if (STORE) {
            const short* pl = xlo + r * D + kg * 8;
            #pragma unroll
            for (int kt = 0; kt < 2; ++kt)
                bl[i][kt] = *reinterpret_cast<const bf16x8*>(pl + kt * 32);
        }
    }

    __shared__ float red[NW][TMB];
    __shared__ float rlds[TMB];
    __shared__ float buf[2][2048];   // phase-2 staging (16 KB, double-buffered)

    float rinv0 = 0.f, rinv1 = 0.f;
    if (STORE) {
        if (t < TMB) {
            const int R = rbase + row0 + t;
            const f32x4 pp = *reinterpret_cast<const f32x4*>(parts + (size_t)R * CSPL);
            const float sum = (pp[0] + pp[1]) + (pp[2] + pp[3]);
            // replay phase1's single-product diag term in matching bf16 arithmetic
            float s1 = 0.f;
            #pragma unroll
            for (int kc = 0; kc < D / 8; ++kc) {
                const bf16x8 hsv = *reinterpret_cast<const bf16x8*>(xhs + (size_t)R * D + kc * 8);
                const bf16x8 hv  = *reinterpret_cast<const bf16x8*>(xhi + (size_t)R * D + kc * 8);
                #pragma unroll
                for (int j = 0; j < 8; ++j)
                    s1 += bf2f((unsigned short)hsv[j]) * bf2f((unsigned short)hv[j]);
            }
            const float cR = csq[R];
            const float e1d = __builtin_amdgcn_exp2f(s1 + cR);
            const float etd = __builtin_amdgcn_exp2f(-cR);   // true rescaled diagonal
            rlds[t] = 1.0f / (sum - e1d + etd);
        }
        __syncthreads();
        rinv0 = rlds[lr];
        rinv1 = rlds[16 + lr];
    }

    float rs0 = 0.f, rs1 = 0.f;
    const int cb0 = s * COLS + w * 16;

    #pragma unroll 2
    for (int j = 0; j < TILES; ++j) {
        const int col = cb0 + j * (NW * 16);
        const int c = rbase + col;

        const short* pa_h = xhs + (size_t)(c + lr) * D + kg * 8;
        const bf16x8 ah0 = *reinterpret_cast<const bf16x8*>(pa_h);
        const bf16x8 ah1 = *reinterpret_cast<const bf16x8*>(pa_h + 32);
        const f32x4 c4 = *reinterpret_cast<const f32x4*>(csq + c + kg * 4);

        f32x4 acc0 = c4, acc1 = c4;
        // single product ah.bh (both phases)
        acc0 = __builtin_amdgcn_mfma_f32_16x16x32_bf16(ah0, bh[0][0], acc0, 0, 0, 0);
        acc0 = __builtin_amdgcn_mfma_f32_16x16x32_bf16(ah1, bh[0][1], acc0, 0, 0, 0);
        acc1 = __builtin_amdgcn_mfma_f32_16x16x32_bf16(ah0, bh[1][0], acc1, 0, 0, 0);
        acc1 = __builtin_amdgcn_mfma_f32_16x16x32_bf16(ah1, bh[1][1], acc1, 0, 0, 0);

        if (STORE) {
            // products 2 and 3 for full precision: ah.bl + al.bh
            const short* pa_l = xls + (size_t)(c + lr) * D + kg * 8;
            const bf16x8 al0 = *reinterpret_cast<const bf16x8*>(pa_l);
            const bf16x8 al1 = *reinterpret_cast<const bf16x8*>(pa_l + 32);
            acc0 = __builtin_amdgcn_mfma_f32_16x16x32_bf16(ah0, bl[0][0], acc0, 0, 0, 0);
            acc0 = __builtin_amdgcn_mfma_f32_16x16x32_bf16(ah1, bl[0][1], acc0, 0, 0, 0);
            acc0 = __builtin_amdgcn_mfma_f32_16x16x32_bf16(al0, bh[0][0], acc0, 0, 0, 0);
            acc0 = __builtin_amdgcn_mfma_f32_16x16x32_bf16(al1, bh[0][1], acc0, 0, 0, 0);
            acc1 = __builtin_amdgcn_mfma_f32_16x16x32_bf16(ah0, bl[1][0], acc1, 0, 0, 0);
            acc1 = __builtin_amdgcn_mfma_f32_16x16x32_bf16(ah1, bl[1][1], acc1, 0, 0, 0);
            acc1 = __builtin_amdgcn_mfma_f32_16x16x32_bf16(al0, bh[1][0], acc1, 0, 0, 0);
            acc1 = __builtin_amdgcn_mfma_f32_16x16x32_bf16(al1, bh[1][1], acc1, 0, 0, 0);

            f32x4 o0, o1;
            #pragma unroll
            for (int q = 0; q < 4; ++q) {
                o0[q] = __builtin_amdgcn_exp2f(acc0[q]) * rinv0;
                o1[q] = __builtin_amdgcn_exp2f(acc1[q]) * rinv1;
            }
            float* bj = buf[j & 1];
            *reinterpret_cast<f32x4*>(bj + lidx(w, kg, lr, 0)) = o0;
            *reinterpret_cast<f32x4*>(bj + lidx(w, kg, lr, 1)) = o1;
            __syncthreads();
            // linear nontemporal stores: 2 rounds x (wave = 4 rows x 64 cols)
            const int scol = s * COLS + j * (NW * 16);
            #pragma unroll
            for (int p = 0; p < 2; ++p) {
                const int f = p * 1024 + t * 4;
                const int row = f >> 6;
                const int cl = f & 63;
                const f32x4 v = *reinterpret_cast<const f32x4*>(
                    bj + lidx(cl >> 4, (cl >> 2) & 3, row & 15, row >> 4));
                __builtin_nontemporal_store(v, reinterpret_cast<f32x4*>(
                    out + (size_t)(rbase + row0 + row) * N + scol + cl));
            }
        } else {
            #pragma unroll
            for (int q = 0; q < 4; ++q) {
                rs0 += __builtin_amdgcn_exp2f(acc0[q]);
                rs1 += __builtin_amdgcn_exp2f(acc1[q]);
            }
        }
    }

    if (!STORE) {
        // lanes sharing an output row differ in kg (lane>>4)
        rs0 += __shfl_xor(rs0, 16, 64); rs0 += __shfl_xor(rs0, 32, 64);
        rs1 += __shfl_xor(rs1, 16, 64); rs1 += __shfl_xor(rs1, 32, 64);
        if (lane < 16) { red[w][lr] = rs0; red[w][16 + lr] = rs1; }
        __syncthreads();
        if (t < TMB) {
            const float sum = (red[0][t] + red[1][t]) + (red[2][t] + red[3][t]);
            parts[(size_t)(rbase + row0 + t) * CSPL + s] = sum;
        }
    }
}

extern "C" void kernel_launch(void* const* d_in, const int* in_sizes, int n_in,
                              void* d_out, int out_size, void* d_ws, size_t ws_size,
                              hipStream_t stream) {
    const float* x = (const float*)d_in[0];
    float* out = (float*)d_out;

    constexpr int NE = NB * N * D;       // 1048576 elements
    short* xhi = (short*)d_ws;
    short* xlo = xhi + NE;
    short* xhs = xlo + NE;
    short* xls = xhs + NE;
    float* csq = (float*)(xls + NE);     // NB*N floats
    float* parts = csq + NB * N;         // NB*N*CSPL floats

    hipLaunchKernelGGL(prep_kernel, dim3(NB * N / 32), dim3(THREADS), 0, stream,
                       x, xhi, xlo, xhs, xls, csq);

    dim3 grid(N / TMB, NB, CSPL);        // 128 x 4 x 4 = 2048 blocks

    // phase 1 twice (idempotent): isolates p1 in the timing decomposition
    hipLaunchKernelGGL((sweep_kernel<false>), grid, dim3(THREADS), 0, stream,
                       xhi, xlo, xhs, xls, csq, parts, out);
    hipLaunchKernelGGL((sweep_kernel<false>), grid, dim3(THREADS), 0, stream,
                       xhi, xlo, xhs, xls, csq, parts, out);

    // phase 2 three times (idempotent): isolates p2
    hipLaunchKernelGGL((sweep_kernel<true>), grid, dim3(THREADS), 0, stream,
                       xhi, xlo, xhs, xls, csq, parts, out);
    hipLaunchKernelGGL((sweep_kernel<true>), grid, dim3(THREADS), 0, stream,
                       xhi, xlo, xhs, xls, csq, parts, out);
    hipLaunchKernelGGL((sweep_kernel<true>), grid, dim3(THREADS), 0, stream,
                       xhi, xlo, xhs, xls, csq, parts, out);
}

// Round 10
// 134.544 us; speedup vs baseline: 2.6000x; 2.6000x over previous
//
#include <hip/hip_runtime.h>
#include <math.h>

// SelfSimilarity — R10 = R7 EXACTLY except phase-2 stores are REGULAR (not
// nontemporal). A/B vs R7's 132.0 us. Decomposition (R9): prep~4, p1~38, p2~90.
// p2's effective write BW ~3 TB/s vs fill's 6.7 TB/s with regular stores ->
// hypothesis: the NT hint defeats L2 write combining on gfx950.
//
// out[b,n,m] = softmax_m( -(|x_n|^2+|x_m|^2-2 x_n.x_m)/T )
//            = e_m / sum_m e_m,   e_m = exp2( kexp*dot(x_n,x_m) - 0.5*kexp*|x_m|^2 )
// phase1 (rowsum): SINGLE product ah.bh; diagonal error corrected exactly at
//   normalization: sum' = sum - e1_diag + exp2(-csq[R]) (true rescaled diagonal).
// phase2 (store): 3-product ah.bh+ah.bl+al.bh; rinv folded pre-LDS,
//   LDS-staged epilogue -> linear float4 stores.

constexpr int NB = 4;
constexpr int N = 4096;
constexpr int D = 64;
constexpr float TEMP = 13.544f;
constexpr int CSPL = 4;
constexpr int COLS = N / CSPL;           // 1024 cols per block
constexpr int TMB = 32;                  // rows per block
constexpr int NW = 4;
constexpr int THREADS = 256;
constexpr int TILES = COLS / (NW * 16);  // 16 col-tiles (of 64 cols) per block

typedef __attribute__((ext_vector_type(8))) short bf16x8;
typedef __attribute__((ext_vector_type(4))) float f32x4;

__device__ __forceinline__ unsigned short f2bf(float f) {
    unsigned int u = __builtin_bit_cast(unsigned int, f);
    u += 0x7FFFu + ((u >> 16) & 1u);   // RNE
    return (unsigned short)(u >> 16);
}
__device__ __forceinline__ float bf2f(unsigned short h) {
    return __builtin_bit_cast(float, (unsigned int)h << 16);
}

// LDS float-index of the 4-float group written by (wave w, kgroup kg, lanerow lr, acc)
__device__ __forceinline__ int lidx(int w, int kg, int lr, int acc) {
    return ((((w << 6) + (kg << 4) + lr) << 3) + (acc << 2)) ^ (w << 2);
}

// ---------------- Pre-pass: convert + squares ----------------
__global__ __launch_bounds__(THREADS)
void prep_kernel(const float* __restrict__ x,
                 short* __restrict__ xhi, short* __restrict__ xlo,
                 short* __restrict__ xhs, short* __restrict__ xls,
                 float* __restrict__ csq) {
    const int t = threadIdx.x;
    const int lane = t & 63, w = t >> 6;
    const int row = blockIdx.x * 32 + w * 8 + (lane >> 3);
    const int seg = lane & 7;
    const float S = 2.0f * 1.4426950408889634f / TEMP;   // kexp

    const float* p = x + (size_t)row * D + seg * 8;
    const float4 u = *reinterpret_cast<const float4*>(p);
    const float4 v = *reinterpret_cast<const float4*>(p + 4);
    float e[8] = {u.x, u.y, u.z, u.w, v.x, v.y, v.z, v.w};

    float sq = 0.f;
    #pragma unroll
    for (int j = 0; j < 8; ++j) sq += e[j] * e[j];
    sq += __shfl_xor(sq, 1, 64);
    sq += __shfl_xor(sq, 2, 64);
    sq += __shfl_xor(sq, 4, 64);

    bf16x8 h, l, hs, ls;
    #pragma unroll
    for (int j = 0; j < 8; ++j) {
        const unsigned short hb = f2bf(e[j]);
        h[j] = (short)hb;
        l[j] = (short)f2bf(e[j] - bf2f(hb));
        const float es = e[j] * S;
        const unsigned short hsb = f2bf(es);
        hs[j] = (short)hsb;
        ls[j] = (short)f2bf(es - bf2f(hsb));
    }
    const int off = row * D + seg * 8;
    *reinterpret_cast<bf16x8*>(xhi + off) = h;
    *reinterpret_cast<bf16x8*>(xlo + off) = l;
    *reinterpret_cast<bf16x8*>(xhs + off) = hs;
    *reinterpret_cast<bf16x8*>(xls + off) = ls;
    if (seg == 0) csq[row] = -0.5f * S * sq;
}

// ---------------- Main sweep: rowsum / normalize+store ----------------
template<bool STORE>
__global__ __launch_bounds__(THREADS)
void sweep_kernel(const short* __restrict__ xhi, const short* __restrict__ xlo,
                  const short* __restrict__ xhs, const short* __restrict__ xls,
                  const float* __restrict__ csq, float* __restrict__ parts,
                  float* __restrict__ out) {
    const int b = blockIdx.y;
    const int s = blockIdx.z;
    const int row0 = blockIdx.x * TMB;
    const int t = threadIdx.x;
    const int w = t >> 6, lane = t & 63;
    const int lr = lane & 15, kg = lane >> 4;
    const int rbase = b * N;

    // persistent row-side fragments (MFMA B operand), rows row0 + 16*i + lr
    bf16x8 bh[2][2], bl[2][2];
    #pragma unroll
    for (int i = 0; i < 2; ++i) {
        const int r = rbase + row0 + 16 * i + lr;
        const short* ph = xhi + r * D + kg * 8;
        #pragma unroll
        for (int kt = 0; kt < 2; ++kt)
            bh[i][kt] = *reinterpret_cast<const bf16x8*>(ph + kt * 32);
        if (STORE) {
            const short* pl = xlo + r * D + kg * 8;
            #pragma unroll
            for (int kt = 0; kt < 2; ++kt)
                bl[i][kt] = *reinterpret_cast<const bf16x8*>(pl + kt * 32);
        }
    }

    __shared__ float red[NW][TMB];
    __shared__ float rlds[TMB];
    __shared__ float buf[2][2048];   // phase-2 staging (16 KB, double-buffered)

    float rinv0 = 0.f, rinv1 = 0.f;
    if (STORE) {
        if (t < TMB) {
            const int R = rbase + row0 + t;
            const f32x4 pp = *reinterpret_cast<const f32x4*>(parts + (size_t)R * CSPL);
            const float sum = (pp[0] + pp[1]) + (pp[2] + pp[3]);
            // replay phase1's single-product diag term in matching bf16 arithmetic
            float s1 = 0.f;
            #pragma unroll
            for (int kc = 0; kc < D / 8; ++kc) {
                const bf16x8 hsv = *reinterpret_cast<const bf16x8*>(xhs + (size_t)R * D + kc * 8);
                const bf16x8 hv  = *reinterpret_cast<const bf16x8*>(xhi + (size_t)R * D + kc * 8);
                #pragma unroll
                for (int j = 0; j < 8; ++j)
                    s1 += bf2f((unsigned short)hsv[j]) * bf2f((unsigned short)hv[j]);
            }
            const float cR = csq[R];
            const float e1d = __builtin_amdgcn_exp2f(s1 + cR);
            const float etd = __builtin_amdgcn_exp2f(-cR);   // true rescaled diagonal
            rlds[t] = 1.0f / (sum - e1d + etd);
        }
        __syncthreads();
        rinv0 = rlds[lr];
        rinv1 = rlds[16 + lr];
    }

    float rs0 = 0.f, rs1 = 0.f;
    const int cb0 = s * COLS + w * 16;

    #pragma unroll 2
    for (int j = 0; j < TILES; ++j) {
        const int col = cb0 + j * (NW * 16);
        const int c = rbase + col;

        const short* pa_h = xhs + (size_t)(c + lr) * D + kg * 8;
        const bf16x8 ah0 = *reinterpret_cast<const bf16x8*>(pa_h);
        const bf16x8 ah1 = *reinterpret_cast<const bf16x8*>(pa_h + 32);
        const f32x4 c4 = *reinterpret_cast<const f32x4*>(csq + c + kg * 4);

        f32x4 acc0 = c4, acc1 = c4;
        // single product ah.bh (both phases)
        acc0 = __builtin_amdgcn_mfma_f32_16x16x32_bf16(ah0, bh[0][0], acc0, 0, 0, 0);
        acc0 = __builtin_amdgcn_mfma_f32_16x16x32_bf16(ah1, bh[0][1], acc0, 0, 0, 0);
        acc1 = __builtin_amdgcn_mfma_f32_16x16x32_bf16(ah0, bh[1][0], acc1, 0, 0, 0);
        acc1 = __builtin_amdgcn_mfma_f32_16x16x32_bf16(ah1, bh[1][1], acc1, 0, 0, 0);

        if (STORE) {
            // products 2 and 3 for full precision: ah.bl + al.bh
            const short* pa_l = xls + (size_t)(c + lr) * D + kg * 8;
            const bf16x8 al0 = *reinterpret_cast<const bf16x8*>(pa_l);
            const bf16x8 al1 = *reinterpret_cast<const bf16x8*>(pa_l + 32);
            acc0 = __builtin_amdgcn_mfma_f32_16x16x32_bf16(ah0, bl[0][0], acc0, 0, 0, 0);
            acc0 = __builtin_amdgcn_mfma_f32_16x16x32_bf16(ah1, bl[0][1], acc0, 0, 0, 0);
            acc0 = __builtin_amdgcn_mfma_f32_16x16x32_bf16(al0, bh[0][0], acc0, 0, 0, 0);
            acc0 = __builtin_amdgcn_mfma_f32_16x16x32_bf16(al1, bh[0][1], acc0, 0, 0, 0);
            acc1 = __builtin_amdgcn_mfma_f32_16x16x32_bf16(ah0, bl[1][0], acc1, 0, 0, 0);
            acc1 = __builtin_amdgcn_mfma_f32_16x16x32_bf16(ah1, bl[1][1], acc1, 0, 0, 0);
            acc1 = __builtin_amdgcn_mfma_f32_16x16x32_bf16(al0, bh[1][0], acc1, 0, 0, 0);
            acc1 = __builtin_amdgcn_mfma_f32_16x16x32_bf16(al1, bh[1][1], acc1, 0, 0, 0);

            f32x4 o0, o1;
            #pragma unroll
            for (int q = 0; q < 4; ++q) {
                o0[q] = __builtin_amdgcn_exp2f(acc0[q]) * rinv0;
                o1[q] = __builtin_amdgcn_exp2f(acc1[q]) * rinv1;
            }
            float* bj = buf[j & 1];
            *reinterpret_cast<f32x4*>(bj + lidx(w, kg, lr, 0)) = o0;
            *reinterpret_cast<f32x4*>(bj + lidx(w, kg, lr, 1)) = o1;
            __syncthreads();
            // linear stores (REGULAR, not NT): 2 rounds x (wave = 4 rows x 64 cols)
            const int scol = s * COLS + j * (NW * 16);
            #pragma unroll
            for (int p = 0; p < 2; ++p) {
                const int f = p * 1024 + t * 4;
                const int row = f >> 6;
                const int cl = f & 63;
                const f32x4 v = *reinterpret_cast<const f32x4*>(
                    bj + lidx(cl >> 4, (cl >> 2) & 3, row & 15, row >> 4));
                *reinterpret_cast<f32x4*>(
                    out + (size_t)(rbase + row0 + row) * N + scol + cl) = v;
            }
        } else {
            #pragma unroll
            for (int q = 0; q < 4; ++q) {
                rs0 += __builtin_amdgcn_exp2f(acc0[q]);
                rs1 += __builtin_amdgcn_exp2f(acc1[q]);
            }
        }
    }

    if (!STORE) {
        // lanes sharing an output row differ in kg (lane>>4)
        rs0 += __shfl_xor(rs0, 16, 64); rs0 += __shfl_xor(rs0, 32, 64);
        rs1 += __shfl_xor(rs1, 16, 64); rs1 += __shfl_xor(rs1, 32, 64);
        if (lane < 16) { red[w][lr] = rs0; red[w][16 + lr] = rs1; }
        __syncthreads();
        if (t < TMB) {
            const float sum = (red[0][t] + red[1][t]) + (red[2][t] + red[3][t]);
            parts[(size_t)(rbase + row0 + t) * CSPL + s] = sum;
        }
    }
}

extern "C" void kernel_launch(void* const* d_in, const int* in_sizes, int n_in,
                              void* d_out, int out_size, void* d_ws, size_t ws_size,
                              hipStream_t stream) {
    const float* x = (const float*)d_in[0];
    float* out = (float*)d_out;

    constexpr int NE = NB * N * D;       // 1048576 elements
    short* xhi = (short*)d_ws;
    short* xlo = xhi + NE;
    short* xhs = xlo + NE;
    short* xls = xhs + NE;
    float* csq = (float*)(xls + NE);     // NB*N floats
    float* parts = csq + NB * N;         // NB*N*CSPL floats

    hipLaunchKernelGGL(prep_kernel, dim3(NB * N / 32), dim3(THREADS), 0, stream,
                       x, xhi, xlo, xhs, xls, csq);

    dim3 grid(N / TMB, NB, CSPL);        // 128 x 4 x 4 = 2048 blocks
    hipLaunchKernelGGL((sweep_kernel<false>), grid, dim3(THREADS), 0, stream,
                       xhi, xlo, xhs, xls, csq, parts, out);
    hipLaunchKernelGGL((sweep_kernel<true>), grid, dim3(THREADS), 0, stream,
                       xhi, xlo, xhs, xls, csq, parts, out);
}